// Round 6
// baseline (430.275 us; speedup 1.0000x reference)
//
#include <hip/hip_runtime.h>
#include <hip/hip_bf16.h>
#include <math.h>

typedef __bf16 bf16_t;
typedef __bf16 bf16x8 __attribute__((ext_vector_type(8)));
typedef float  f32x4  __attribute__((ext_vector_type(4)));

#define WPB 4    // waves per block

// MFMA 16x16x32 layouts (m89/m120-verified):
//   A: lane(m = lane&15, q = lane>>4) holds A[m][8q+j], j=0..7
//   B: lane(n = lane&15, q)           holds B[8q+j][n]
//   C: lane(n = lane&15, q) reg r     holds C[4q+r][n]
//
// r4: operand-SWAPPED MFMA (y^T = W^T x^T) -> C row-per-lane, coalesced rgb
//     store, bias rides in as the MFMA C operand.
// r6: K-PERMUTATION INVARIANCE — ch(q,c,j) = 16*(2c+(j>>2)) + 4q + (j&3)
//     makes the next layer's B-frag = relu_pack(acc[2c],acc[2c+1]) in-lane.
// r7: (256,2) spill relief + depth-2 prefetch.
// r8: dual-tile ILP — NEUTRAL => not chain-latency-bound; memory service
//     rate to this kernel (~8.25 B/cy/CU) is 23% below the fill's 10.7.
//
// r9: STREAM CONTIGUITY. Strided persistent scheduling made every wave jump
// 8 MB per iteration (2048 scattered page-opens per iter grid-wide; 4 KB per
// page touch). Fills reach 6.6 TB/s at 10% occupancy with long sequential
// runs => contiguity, not TLP, is what we lack. Assign each wave a
// CONTIGUOUS 32-pair (128 KB) slab; reads and rgb writes become sequential
// streams. Also: feat loads now plain cached loads (NT evict-first could
// defeat L2 half-line merging of the 16B-granule frag loads); NT kept on
// write-once stores.
//
// r3 (kept): pin() stops LLVM rematerializing invariant weight loads in-loop.

__device__ __forceinline__ void pin8(bf16x8& x) {
    f32x4 t = __builtin_bit_cast(f32x4, x);
    asm volatile("" : "+v"(t));
    x = __builtin_bit_cast(bf16x8, t);
}
__device__ __forceinline__ void pin4(f32x4& x) { asm volatile("" : "+v"(x)); }

__device__ __forceinline__ bf16x8 cvt8(f32x4 lo, f32x4 hi) {
    bf16x8 r;
    #pragma unroll
    for (int j = 0; j < 4; ++j) { r[j] = (bf16_t)lo[j]; r[4 + j] = (bf16_t)hi[j]; }
    return r;
}

// ReLU + bf16 pair-pack (v_cvt_pk_bf16_f32): acc pair -> next-layer B-frag chunk.
__device__ __forceinline__ bf16x8 relu_pack(const f32x4 a, const f32x4 b) {
    bf16x8 r;
    #pragma unroll
    for (int j = 0; j < 4; ++j) {
        r[j]     = (bf16_t)fmaxf(a[j], 0.0f);
        r[4 + j] = (bf16_t)fmaxf(b[j], 0.0f);
    }
    return r;
}

__global__ __launch_bounds__(256, 2)   // cap 256 VGPR: zero spill; 8 waves/CU
void ngp_mlp_kernel(const float* __restrict__ feat,
                    const float* __restrict__ W0,
                    const float* __restrict__ b0,
                    const float* __restrict__ W1,
                    const float* __restrict__ b1,
                    const float* __restrict__ Ws,
                    const float* __restrict__ bs,
                    const float* __restrict__ Wr,
                    const float* __restrict__ br,
                    float* __restrict__ out_sigma,
                    float* __restrict__ out_rgb,
                    int num_pairs, int pairs_per_wave)
{
    const int tid  = threadIdx.x;
    const int wid  = tid >> 6;
    const int lane = tid & 63;
    const int n    = lane & 15;
    const int q    = lane >> 4;

    // ---------- one-time weight fragment construction (L2/L3-resident) ----------
    bf16x8 w0f[4];                       // W0 [32 x 64]: canonical gather
    #pragma unroll
    for (int t = 0; t < 4; ++t)
        #pragma unroll
        for (int j = 0; j < 8; ++j)
            w0f[t][j] = (bf16_t)W0[(8*q + j)*64 + 16*t + n];

    // permuted row gathers: contraction slot (q,c,j) carries channel ch(q,c,j)
    bf16x8 w1f[4][2];                    // W1 [64 x 64]: tile t, K-chunk c
    #pragma unroll
    for (int t = 0; t < 4; ++t)
        #pragma unroll
        for (int c = 0; c < 2; ++c)
            #pragma unroll
            for (int j = 0; j < 8; ++j) {
                const int ch = 16*(2*c + (j >> 2)) + 4*q + (j & 3);
                w1f[t][c][j] = (bf16_t)W1[ch*64 + 16*t + n];
            }

    bf16x8 whf[2][2];                    // heads: tile0 = Wr^T rows, tile1 row0 = Ws^T
    #pragma unroll
    for (int c = 0; c < 2; ++c)
        #pragma unroll
        for (int j = 0; j < 8; ++j) {
            const int ch = 16*(2*c + (j >> 2)) + 4*q + (j & 3);
            whf[0][c][j] = (bf16_t)Wr[ch*16 + n];
            whf[1][c][j] = (n == 0) ? (bf16_t)Ws[ch] : (bf16_t)0.0f;
        }

    // per-output-channel biases: channel = 16t + 4q + r  -> f32x4 per tile
    f32x4 b0q[4], b1q[4];
    #pragma unroll
    for (int t = 0; t < 4; ++t) {
        b0q[t] = *(const f32x4*)(b0 + 16*t + 4*q);
        b1q[t] = *(const f32x4*)(b1 + 16*t + 4*q);
    }
    f32x4 brq = *(const f32x4*)(br + 4*q);
    f32x4 sIn = (f32x4){ (q == 0) ? (bs[0] - 1.0f) : 0.0f, 0.0f, 0.0f, 0.0f };

    // ---- pin everything: kill invariant-load rematerialization ----
    #pragma unroll
    for (int t = 0; t < 4; ++t) pin8(w0f[t]);
    #pragma unroll
    for (int t = 0; t < 4; ++t)
        #pragma unroll
        for (int c = 0; c < 2; ++c) pin8(w1f[t][c]);
    #pragma unroll
    for (int h = 0; h < 2; ++h)
        #pragma unroll
        for (int c = 0; c < 2; ++c) pin8(whf[h][c]);
    #pragma unroll
    for (int t = 0; t < 4; ++t) { pin4(b0q[t]); pin4(b1q[t]); }
    pin4(brq); pin4(sIn);

    // ---------- main loop: contiguous slab of pairs per wave ----------
    const int w     = blockIdx.x * WPB + wid;       // global wave id
    int       p     = w * pairs_per_wave;           // slab start
    const int pend  = (p + pairs_per_wave < num_pairs) ? p + pairs_per_wave
                                                       : num_pairs;
    if (p >= num_pairs) return;
    const int plast = pend - 1;

    // depth-2 prefetch pipeline over consecutive pairs (cached loads)
    const float* fpc = feat + ((size_t)p*32 + n)*32 + 8*q;
    f32x4 cAlo = *((const f32x4*)fpc);
    f32x4 cAhi = *((const f32x4*)fpc + 1);
    f32x4 cBlo = *((const f32x4*)(fpc + 512));
    f32x4 cBhi = *((const f32x4*)(fpc + 512) + 1);

    const int p1 = (p + 1 < pend) ? p + 1 : plast;
    const float* fp1 = feat + ((size_t)p1*32 + n)*32 + 8*q;
    f32x4 nAlo = *((const f32x4*)fp1);
    f32x4 nAhi = *((const f32x4*)fp1 + 1);
    f32x4 nBlo = *((const f32x4*)(fp1 + 512));
    f32x4 nBhi = *((const f32x4*)(fp1 + 512) + 1);

    while (true) {
        // issue prefetch for p+2 (clamped) — sequential +4 KiB stream
        const int  p2 = p + 2;
        const int  pf = (p2 < pend) ? p2 : plast;
        const float* fpn = feat + ((size_t)pf*32 + n)*32 + 8*q;
        f32x4 mAlo = *((const f32x4*)fpn);
        f32x4 mAhi = *((const f32x4*)fpn + 1);
        f32x4 mBlo = *((const f32x4*)(fpn + 512));
        f32x4 mBhi = *((const f32x4*)(fpn + 512) + 1);

        const int rowA = p * 32;          // tile 2p   -> rows rowA..rowA+15
        const int rowB = rowA + 16;       // tile 2p+1 -> rows rowB..rowB+15
        bf16x8 a0A = cvt8(cAlo, cAhi);
        bf16x8 a0B = cvt8(cBlo, cBhi);

        // ---- layer 0 (swapped), both tiles interleaved ----
        f32x4 acc0A[4], acc0B[4];
        #pragma unroll
        for (int t = 0; t < 4; ++t) {
            acc0A[t] = __builtin_amdgcn_mfma_f32_16x16x32_bf16(w0f[t], a0A, b0q[t], 0, 0, 0);
            acc0B[t] = __builtin_amdgcn_mfma_f32_16x16x32_bf16(w0f[t], a0B, b0q[t], 0, 0, 0);
        }

        bf16x8 a1A[2], a1B[2];
        a1A[0] = relu_pack(acc0A[0], acc0A[1]);
        a1B[0] = relu_pack(acc0B[0], acc0B[1]);
        a1A[1] = relu_pack(acc0A[2], acc0A[3]);
        a1B[1] = relu_pack(acc0B[2], acc0B[3]);

        // ---- layer 1 (swapped, permuted K), both tiles interleaved ----
        f32x4 acc1A[4], acc1B[4];
        #pragma unroll
        for (int t = 0; t < 4; ++t) {
            acc1A[t] = __builtin_amdgcn_mfma_f32_16x16x32_bf16(w1f[t][0], a1A[0], b1q[t], 0, 0, 0);
            acc1B[t] = __builtin_amdgcn_mfma_f32_16x16x32_bf16(w1f[t][0], a1B[0], b1q[t], 0, 0, 0);
            acc1A[t] = __builtin_amdgcn_mfma_f32_16x16x32_bf16(w1f[t][1], a1A[1], acc1A[t], 0, 0, 0);
            acc1B[t] = __builtin_amdgcn_mfma_f32_16x16x32_bf16(w1f[t][1], a1B[1], acc1B[t], 0, 0, 0);
        }

        bf16x8 ahA[2], ahB[2];
        ahA[0] = relu_pack(acc1A[0], acc1A[1]);
        ahB[0] = relu_pack(acc1B[0], acc1B[1]);
        ahA[1] = relu_pack(acc1A[2], acc1A[3]);
        ahB[1] = relu_pack(acc1B[2], acc1B[3]);

        // ---- heads, both tiles interleaved ----
        f32x4 aRA = __builtin_amdgcn_mfma_f32_16x16x32_bf16(whf[0][0], ahA[0], brq, 0, 0, 0);
        f32x4 aRB = __builtin_amdgcn_mfma_f32_16x16x32_bf16(whf[0][0], ahB[0], brq, 0, 0, 0);
        aRA       = __builtin_amdgcn_mfma_f32_16x16x32_bf16(whf[0][1], ahA[1], aRA, 0, 0, 0);
        aRB       = __builtin_amdgcn_mfma_f32_16x16x32_bf16(whf[0][1], ahB[1], aRB, 0, 0, 0);
        f32x4 aSA = __builtin_amdgcn_mfma_f32_16x16x32_bf16(whf[1][0], ahA[0], sIn, 0, 0, 0);
        f32x4 aSB = __builtin_amdgcn_mfma_f32_16x16x32_bf16(whf[1][0], ahB[0], sIn, 0, 0, 0);
        aSA       = __builtin_amdgcn_mfma_f32_16x16x32_bf16(whf[1][1], ahA[1], aSA, 0, 0, 0);
        aSB       = __builtin_amdgcn_mfma_f32_16x16x32_bf16(whf[1][1], ahB[1], aSB, 0, 0, 0);

        // ---- rgb: lane(n,q) holds rgb[n][4q..4q+3] -> coalesced dwordx4 x2 ----
        __builtin_nontemporal_store(aRA, (f32x4*)(out_rgb + ((size_t)rowA + n) * 16 + 4*q));
        __builtin_nontemporal_store(aRB, (f32x4*)(out_rgb + ((size_t)rowB + n) * 16 + 4*q));

        // ---- sigma: q==0 lanes hold sigma[n] in reg 0; branchless fast softplus ----
        if (q == 0) {
            float zA  = aSA[0];
            float eA  = __builtin_exp2f(-fabsf(zA) * 1.44269504f);
            float spA = fmaxf(zA, 0.0f) + __builtin_log2f(1.0f + eA) * 0.69314718f;
            __builtin_nontemporal_store(spA, out_sigma + rowA + n);
            float zB  = aSB[0];
            float eB  = __builtin_exp2f(-fabsf(zB) * 1.44269504f);
            float spB = fmaxf(zB, 0.0f) + __builtin_log2f(1.0f + eB) * 0.69314718f;
            __builtin_nontemporal_store(spB, out_sigma + rowB + n);
        }

        if (p + 1 >= pend) break;
        ++p;
        cAlo = nAlo; cAhi = nAhi; cBlo = nBlo; cBhi = nBhi;
        nAlo = mAlo; nAhi = mAhi; nBlo = mBlo; nBhi = mBhi;
    }
}

extern "C" void kernel_launch(void* const* d_in, const int* in_sizes, int n_in,
                              void* d_out, int out_size, void* d_ws, size_t ws_size,
                              hipStream_t stream) {
    const float* feat = (const float*)d_in[0];
    const float* W0   = (const float*)d_in[1];
    const float* b0   = (const float*)d_in[2];
    const float* W1   = (const float*)d_in[3];
    const float* b1   = (const float*)d_in[4];
    const float* Ws   = (const float*)d_in[5];
    const float* bs   = (const float*)d_in[6];
    const float* Wr   = (const float*)d_in[7];
    const float* br   = (const float*)d_in[8];

    const int B         = in_sizes[0] / 32;      // 2,097,152
    const int num_pairs = B / 32;                // 65,536 tile-pairs (32 rows each)

    float* out_sigma = (float*)d_out;            // [B]
    float* out_rgb   = out_sigma + B;            // [B,16]

    // 2 blocks/CU resident (launch_bounds(256,2)) x 256 CUs = 2048 waves.
    // Each wave owns a CONTIGUOUS 32-pair (128 KiB) slab: sequential streams.
    const int blocks = 512;
    const int waves  = blocks * WPB;
    const int ppw    = (num_pairs + waves - 1) / waves;   // 32
    ngp_mlp_kernel<<<blocks, 256, 0, stream>>>(feat, W0, b0, W1, b1, Ws, bs, Wr, br,
                                               out_sigma, out_rgb,
                                               num_pairs, ppw);
}